// Round 8
// baseline (50.649 us; speedup 1.0000x reference)
//
#include <hip/hip_runtime.h>
#include <math.h>

#define NGRAPH 128
#define NNODE  200
#define FIN    200
#define DIM    32
#define EPER   6400
#define ETOT   819200
#define KP1    100
#define KP2    50

// sW layout offsets (floats)
#define W1B_OFF  0
#define W2A_OFF  1024
#define W2B_OFF  2048
#define B1A_OFF  3072
#define B1B_OFF  3104
#define B2A_OFF  3136
#define B2B_OFF  3168
#define PW1_OFF  3200
#define PW2_OFF  3232
#define NRM1_OFF 3264
#define NRM2_OFF 3265
#define SW_SIZE  3280

// XOR chunk swizzle for [row][32]-float LDS tiles.
__device__ __forceinline__ int swz(int row, int chunk) {
  return (row << 5) + (((chunk ^ ((row >> 2) & 7))) << 2);
}

__device__ __forceinline__ void spin_eq(const int* f, int target) {
  while (__hip_atomic_load(f, __ATOMIC_RELAXED,
                           __HIP_MEMORY_SCOPE_WORKGROUP) != target)
    __builtin_amdgcn_s_sleep(1);
}

// [ROWS]x32 @ 32x32, 2 rows/thread (tid < ROWS*2).
// FUSE: A-operand = relu(A[p] + A2[p] + fb[chunk]) on the fly (GIN add+relu).
// SCORE: also emit pool score tanh(dot(h_row, pw)/nrm) via 4-lane shfl reduce.
template <int ROWS, bool RELU, bool BIAS, bool FUSE, bool SCORE>
__device__ __forceinline__ void mm2r(const float* __restrict__ A,
                                     const float* __restrict__ A2,
                                     const float* __restrict__ fb,
                                     const float* __restrict__ W,
                                     float* __restrict__ O,
                                     const float* __restrict__ bias,
                                     const float* __restrict__ pw,
                                     const float* __restrict__ nrmp,
                                     float* __restrict__ scoreOut, int tid) {
  if (tid < ROWS * 2) {
    const int rg = tid >> 2, cg = tid & 3;
    const int r0 = rg * 2, d0 = cg * 8;
    float acc[2][8];
#pragma unroll
    for (int r = 0; r < 2; ++r)
#pragma unroll
      for (int c = 0; c < 8; ++c) acc[r][c] = 0.f;
#pragma unroll
    for (int kc = 0; kc < 8; ++kc) {
      float4 av[2];
#pragma unroll
      for (int r = 0; r < 2; ++r) {
        const int p = swz(r0 + r, kc);
        float4 v = *(const float4*)&A[p];
        if (FUSE) {
          const float4 u = *(const float4*)&A2[p];
          const float4 b = *(const float4*)&fb[kc * 4];
          v.x = fmaxf(v.x + u.x + b.x, 0.f);
          v.y = fmaxf(v.y + u.y + b.y, 0.f);
          v.z = fmaxf(v.z + u.z + b.z, 0.f);
          v.w = fmaxf(v.w + u.w + b.w, 0.f);
        }
        av[r] = v;
      }
#pragma unroll
      for (int j = 0; j < 4; ++j) {
        const int k = kc * 4 + j;
        const float4 wa = *(const float4*)&W[k * 32 + d0];
        const float4 wb = *(const float4*)&W[k * 32 + d0 + 4];
#pragma unroll
        for (int r = 0; r < 2; ++r) {
          const float xs = (j == 0) ? av[r].x : (j == 1) ? av[r].y
                                  : (j == 2) ? av[r].z : av[r].w;
          acc[r][0] += xs * wa.x; acc[r][1] += xs * wa.y;
          acc[r][2] += xs * wa.z; acc[r][3] += xs * wa.w;
          acc[r][4] += xs * wb.x; acc[r][5] += xs * wb.y;
          acc[r][6] += xs * wb.z; acc[r][7] += xs * wb.w;
        }
      }
    }
    float dot[2] = {0.f, 0.f};
#pragma unroll
    for (int r = 0; r < 2; ++r) {
      float v[8];
#pragma unroll
      for (int c = 0; c < 8; ++c) {
        float t = acc[r][c];
        if (BIAS) t += bias[d0 + c];
        if (RELU) t = fmaxf(t, 0.f);
        v[c] = t;
      }
      if (SCORE) {
        float d = 0.f;
#pragma unroll
        for (int c = 0; c < 8; ++c) d += v[c] * pw[d0 + c];
        dot[r] = d;
      }
      float4 o0, o1;
      o0.x = v[0]; o0.y = v[1]; o0.z = v[2]; o0.w = v[3];
      o1.x = v[4]; o1.y = v[5]; o1.z = v[6]; o1.w = v[7];
      *(float4*)&O[swz(r0 + r, cg * 2)] = o0;
      *(float4*)&O[swz(r0 + r, cg * 2 + 1)] = o1;
    }
    if (SCORE) {
      dot[0] += __shfl_xor(dot[0], 1); dot[0] += __shfl_xor(dot[0], 2);
      dot[1] += __shfl_xor(dot[1], 1); dot[1] += __shfl_xor(dot[1], 2);
      if ((tid & 3) == 0) {
        const float nrm = *nrmp;
        scoreOut[r0] = tanhf(dot[0] / nrm);
        scoreOut[r0 + 1] = tanhf(dot[1] / nrm);
      }
    }
  }
}

// exclusive prefix over 256 counters (4-padded) by one full wave; lane 0..63
__device__ __forceinline__ void scan_counts(const int* __restrict__ cnt,
                                            int* __restrict__ start, int lane) {
  const int b = lane * 4;
  const int c0 = (cnt[b + 0] + 3) & ~3;
  const int c1 = (cnt[b + 1] + 3) & ~3;
  const int c2 = (cnt[b + 2] + 3) & ~3;
  const int c3 = (cnt[b + 3] + 3) & ~3;
  const int t01 = c0 + c1;
  const int t012 = t01 + c2;
  const int tot = t012 + c3;
  int run = tot;
#pragma unroll
  for (int off = 1; off < 64; off <<= 1) {
    const int t = __shfl_up(run, off);
    if (lane >= off) run += t;
  }
  const int e = run - tot;
  start[b + 0] = e;
  start[b + 1] = e + c0;
  start[b + 2] = e + t01;
  start[b + 3] = e + t012;
}

// 128 node-slots x 8 float4-parts
template <int NN>
__device__ __forceinline__ void aggregate(const float* __restrict__ sYv,
                                          float* __restrict__ sAgv,
                                          const int* __restrict__ sSrcv,
                                          const int* __restrict__ sStartv,
                                          const int* __restrict__ sCntv, int tid) {
  const int slot = tid >> 3, part = tid & 7;
#pragma unroll
  for (int p = 0; p < (NN + 127) / 128; ++p) {
    const int n = p * 128 + slot;
    if (n < NN) {
      const int jb = sStartv[n];
      const int je = jb + sCntv[n];
      float4 a0 = {0, 0, 0, 0}, a1 = {0, 0, 0, 0}, a2 = {0, 0, 0, 0}, a3 = {0, 0, 0, 0};
      int j = jb;
      for (; j + 4 <= je; j += 4) {
        const int4 ss = *(const int4*)&sSrcv[j];
        const float4 v0 = *(const float4*)&sYv[swz(ss.x, part)];
        const float4 v1 = *(const float4*)&sYv[swz(ss.y, part)];
        const float4 v2 = *(const float4*)&sYv[swz(ss.z, part)];
        const float4 v3 = *(const float4*)&sYv[swz(ss.w, part)];
        a0.x += v0.x; a0.y += v0.y; a0.z += v0.z; a0.w += v0.w;
        a1.x += v1.x; a1.y += v1.y; a1.z += v1.z; a1.w += v1.w;
        a2.x += v2.x; a2.y += v2.y; a2.z += v2.z; a2.w += v2.w;
        a3.x += v3.x; a3.y += v3.y; a3.z += v3.z; a3.w += v3.w;
      }
      for (; j < je; ++j) {
        const float4 v = *(const float4*)&sYv[swz(sSrcv[j], part)];
        a0.x += v.x; a0.y += v.y; a0.z += v.z; a0.w += v.w;
      }
      float4 o;
      o.x = (a0.x + a1.x) + (a2.x + a3.x);
      o.y = (a0.y + a1.y) + (a2.y + a3.y);
      o.z = (a0.z + a1.z) + (a2.z + a3.z);
      o.w = (a0.w + a1.w) + (a2.w + a3.w);
      *(float4*)&sAgv[swz(n, part)] = o;
    }
  }
}

// ============ single fused kernel: one block per graph ======
__global__ __launch_bounds__(1024, 1) void gin_fused(
    const float* __restrict__ x, const int* __restrict__ ei,
    const float* __restrict__ w1a, const float* __restrict__ b1a,
    const float* __restrict__ w1b, const float* __restrict__ b1b,
    const float* __restrict__ w2a, const float* __restrict__ b2a,
    const float* __restrict__ w2b, const float* __restrict__ b2b,
    const float* __restrict__ pw1, const float* __restrict__ pw2,
    const float* __restrict__ fc1w, const float* __restrict__ fc1b,
    const float* __restrict__ fc2w, const float* __restrict__ fc2b,
    const float* __restrict__ fc3w, const float* __restrict__ fc3b,
    const float* __restrict__ bn1g, const float* __restrict__ bn1b,
    const float* __restrict__ bn1m, const float* __restrict__ bn1v,
    const float* __restrict__ bn2g, const float* __restrict__ bn2b,
    const float* __restrict__ bn2m, const float* __restrict__ bn2v,
    float* __restrict__ out) {
  __shared__ __align__(16) float sY[6400];    // y1 (swz), later y2
  __shared__ __align__(16) float sAg[6400];   // w1a during proj, then aggr
  __shared__ __align__(16) float sH[6400];    // conv outputs (swz)
  __shared__ __align__(16) float sHp[3200];   // pooled h (swz)
  __shared__ __align__(16) float sW[SW_SIZE];
  __shared__ __align__(16) int sSrc[7040];    // 4-aligned CSR src lists
  __shared__ unsigned short sEdge[6400];      // packed (src<<8)|dst
  __shared__ int sCnt[256], sStart[256], sOfs[256];
  __shared__ int sCnt2[256], sStart2[256], sOfs2[256];
  __shared__ int sFlag[8];
  __shared__ float sScore[256];
  __shared__ int sNewid[256];
  __shared__ float sZ[64];
  __shared__ float sZ1[128];
  __shared__ float sZ2[256];

  const int tid = threadIdx.x;
  const int lane = tid & 63;
  const int g = blockIdx.x;

  // proj geometry + x prefetch registers (live across phase-A barrier)
  const int prg = tid >> 3, pcg = tid & 7;       // proj: 2 rows x 4 cols
  const int pn0 = prg * 2, pd0 = pcg * 4;
  const float* xg = x + ((size_t)g * NNODE + pn0) * FIN;
  float4 pa0, pa1, pb0, pb1;

  // ===== A: minimal staging; proj threads pre-issue first x loads =====
  if (tid < 800) {
    pa0 = *(const float4*)&xg[0];
    pa1 = *(const float4*)&xg[4];
    pb0 = *(const float4*)&xg[FIN];
    pb1 = *(const float4*)&xg[FIN + 4];
  } else if (tid < 832) {
    const int t = tid - 800;
    if (t < 8) sFlag[t] = 0;
    sW[B1A_OFF + t] = b1a[t];
    sW[B1B_OFF + t] = b1b[t];
    sW[B2A_OFF + t] = b2a[t];
    sW[B2B_OFF + t] = b2b[t];
    sW[PW1_OFF + t] = pw1[t];
    sW[PW2_OFF + t] = pw2[t];
  } else {
    // crew (192 thr, waves 13-15): zero counters + stage w1a
    const int t = tid - 832;
    for (int i = t; i < 256; i += 192) {
      sCnt[i] = 0; sOfs[i] = 0; sCnt2[i] = 0; sOfs2[i] = 0;
    }
    for (int i = t; i < 1600; i += 192)
      ((float4*)sAg)[i] = ((const float4*)w1a)[i];
  }
  __syncthreads();

  // ===== B: proj on 800 thr || norms || crew: edges->CSR1->sW staging =====
  if (tid < 800) {
    // y1 = x_g @ w1a : 2 rows x 4 cols/thread, ascending k, prefetch-ahead.
    float a0[4] = {0, 0, 0, 0}, a1[4] = {0, 0, 0, 0};
    for (int k = 0; k < FIN; k += 8) {
      const float4 ca0 = pa0, ca1 = pa1, cb0 = pb0, cb1 = pb1;
      if (k + 8 < FIN) {
        pa0 = *(const float4*)&xg[k + 8];
        pa1 = *(const float4*)&xg[k + 12];
        pb0 = *(const float4*)&xg[FIN + k + 8];
        pb1 = *(const float4*)&xg[FIN + k + 12];
      }
#pragma unroll
      for (int h = 0; h < 2; ++h) {
#pragma unroll
        for (int j = 0; j < 4; ++j) {
          const int kk = k + h * 4 + j;
          const float4 w = *(const float4*)&sAg[kk * 32 + pd0];
          const float s0 = (h == 0) ? ((j == 0) ? ca0.x : (j == 1) ? ca0.y
                                      : (j == 2) ? ca0.z : ca0.w)
                                    : ((j == 0) ? ca1.x : (j == 1) ? ca1.y
                                      : (j == 2) ? ca1.z : ca1.w);
          const float s1 = (h == 0) ? ((j == 0) ? cb0.x : (j == 1) ? cb0.y
                                      : (j == 2) ? cb0.z : cb0.w)
                                    : ((j == 0) ? cb1.x : (j == 1) ? cb1.y
                                      : (j == 2) ? cb1.z : cb1.w);
          a0[0] += s0 * w.x; a0[1] += s0 * w.y;
          a0[2] += s0 * w.z; a0[3] += s0 * w.w;
          a1[0] += s1 * w.x; a1[1] += s1 * w.y;
          a1[2] += s1 * w.z; a1[3] += s1 * w.w;
        }
      }
    }
    float4 o;
    o.x = a0[0]; o.y = a0[1]; o.z = a0[2]; o.w = a0[3];
    *(float4*)&sY[swz(pn0, pcg)] = o;
    o.x = a1[0]; o.y = a1[1]; o.z = a1[2]; o.w = a1[3];
    *(float4*)&sY[swz(pn0 + 1, pcg)] = o;
  } else if (tid == 800) {
    float s = 0.f;
    for (int k = 0; k < 32; ++k) s += pw1[k] * pw1[k];
    sW[NRM1_OFF] = sqrtf(s);
  } else if (tid == 801) {
    float s = 0.f;
    for (int k = 0; k < 32; ++k) s += pw2[k] * pw2[k];
    sW[NRM2_OFF] = sqrtf(s);
  } else if (tid >= 832) {
    const int t = tid - 832;  // 0..191
    // pack edges
    {
      const int eb = g * EPER, nb = g * NNODE;
      for (int i = t; i < EPER / 4; i += 192) {
        const int4 ss = *(const int4*)&ei[eb + i * 4];
        const int4 dd = *(const int4*)&ei[ETOT + eb + i * 4];
        sEdge[i * 4 + 0] = (unsigned short)(((ss.x - nb) << 8) | (dd.x - nb));
        sEdge[i * 4 + 1] = (unsigned short)(((ss.y - nb) << 8) | (dd.y - nb));
        sEdge[i * 4 + 2] = (unsigned short)(((ss.z - nb) << 8) | (dd.z - nb));
        sEdge[i * 4 + 3] = (unsigned short)(((ss.w - nb) << 8) | (dd.w - nb));
      }
    }
    __threadfence_block();
    if (lane == 0) atomicAdd(&sFlag[1], 1);
    spin_eq(&sFlag[1], 3);
    // count in-degree (8 edges per uint4)
    for (int i = t; i < 800; i += 192) {
      const uint4 u = *(const uint4*)&sEdge[i * 8];
      atomicAdd(&sCnt[u.x & 255], 1);
      atomicAdd(&sCnt[(u.x >> 16) & 255], 1);
      atomicAdd(&sCnt[u.y & 255], 1);
      atomicAdd(&sCnt[(u.y >> 16) & 255], 1);
      atomicAdd(&sCnt[u.z & 255], 1);
      atomicAdd(&sCnt[(u.z >> 16) & 255], 1);
      atomicAdd(&sCnt[u.w & 255], 1);
      atomicAdd(&sCnt[(u.w >> 16) & 255], 1);
    }
    __threadfence_block();
    if (lane == 0) atomicAdd(&sFlag[2], 1);
    if (tid >= 960) {  // wave 15 scans
      spin_eq(&sFlag[2], 3);
      scan_counts(sCnt, sStart, tid - 960);
      __threadfence_block();
      if (tid == 960) atomicExch(&sFlag[3], 1);
    }
    spin_eq(&sFlag[3], 1);
    // scatter src ids grouped by dst
    for (int e = t; e < EPER; e += 192) {
      const unsigned short p = sEdge[e];
      sSrc[sStart[p & 255] + atomicAdd(&sOfs[p & 255], 1)] = p >> 8;
    }
    // stage mm weights (needed from phase F)
    for (int i = t; i < 768; i += 192) {
      const float4 v = (i < 256) ? ((const float4*)w1b)[i]
                    : (i < 512) ? ((const float4*)w2a)[i - 256]
                                : ((const float4*)w2b)[i - 512];
      const int off = (i < 256) ? W1B_OFF + i * 4
                    : (i < 512) ? W2A_OFF + (i - 256) * 4
                                : W2B_OFF + (i - 512) * 4;
      *(float4*)&sW[off] = v;
    }
  }
  __syncthreads();

  // ---- E: aggr1 ----
  aggregate<NNODE>(sY, sAg, sSrc, sStart, sCnt, tid);
  __syncthreads();

  // ---- F: h = relu(relu(y1+aggr1+b1a) @ w1b + b1b), score1 fused ----
  mm2r<200, true, true, true, true>(sY, sAg, &sW[B1A_OFF], &sW[W1B_OFF], sH,
                                    &sW[B1B_OFF], &sW[PW1_OFF], &sW[NRM1_OFF],
                                    sScore, tid);
  __syncthreads();

  // ---- H: rank1 (stable descending == lax.top_k) + attn1 + hp1 ----
  if (tid < NNODE * 4) {
    const int n = tid >> 2, q = tid & 3;
    const float s = sScore[n];
    int r = 0;
    for (int m = q * 50; m < q * 50 + 50; ++m) {
      const float sm = sScore[m];
      r += (sm > s) || (sm == s && m < n);
    }
    r += __shfl_xor(r, 1);
    r += __shfl_xor(r, 2);
    if (q == 0) {
      sNewid[n] = (r < KP1) ? r : -1;
      if (r < KP1) out[2 * NGRAPH + g * KP1 + r] = 1.f / (1.f + expf(-s));
    }
    if (r < KP1) {
#pragma unroll
      for (int c = 0; c < 2; ++c) {
        const int ch = q * 2 + c;
        float4 v = *(const float4*)&sH[swz(n, ch)];
        v.x *= s; v.y *= s; v.z *= s; v.w *= s;
        *(float4*)&sHp[swz(r, ch)] = v;
      }
    }
  }
  __syncthreads();

  // ---- I: y2 = hp1 @ w2a (t<200) || x1 readout (wave 4) || CSR2 (512+) ----
  mm2r<KP1, false, false, false, false>(sHp, nullptr, nullptr, &sW[W2A_OFF],
                                        sY, nullptr, nullptr, nullptr, nullptr,
                                        tid);
  if (tid >= 256 && tid < 320) {
    const int l = tid - 256;
    const int idx = l & 31, seg = l >> 5;
    const int ch = idx >> 2, w = idx & 3;
    float m = -INFINITY, s = 0.f;
    for (int r = seg * 50; r < seg * 50 + 50; ++r) {
      const float v = sHp[swz(r, ch) + w];
      m = fmaxf(m, v); s += v;
    }
    m = fmaxf(m, __shfl_xor(m, 32));
    s += __shfl_xor(s, 32);
    if (seg == 0) {
      sZ[idx] = m;
      sZ[32 + idx] = s / (float)KP1;
    }
  } else if (tid >= 512) {
    for (int e = tid - 512; e < EPER; e += 512) {
      const unsigned short p = sEdge[e];
      const int s1 = sNewid[p >> 8], d1 = sNewid[p & 255];
      if (s1 >= 0 && d1 >= 0) atomicAdd(&sCnt2[d1], 1);
    }
    __threadfence_block();
    if (lane == 0) atomicAdd(&sFlag[4], 1);
    if (tid >= 960) {  // wave 15 scans
      spin_eq(&sFlag[4], 8);
      scan_counts(sCnt2, sStart2, tid - 960);
      __threadfence_block();
      if (tid == 960) atomicExch(&sFlag[5], 1);
    }
    spin_eq(&sFlag[5], 1);
    for (int e = tid - 512; e < EPER; e += 512) {
      const unsigned short p = sEdge[e];
      const int s1 = sNewid[p >> 8], d1 = sNewid[p & 255];
      if (s1 >= 0 && d1 >= 0)
        sSrc[sStart2[d1] + atomicAdd(&sOfs2[d1], 1)] = s1;
    }
  }
  __syncthreads();

  // ---- L: aggr2 ----
  aggregate<KP1>(sY, sAg, sSrc, sStart2, sCnt2, tid);
  __syncthreads();

  // ---- M: hc2 = relu(relu(y2+aggr2+b2a) @ w2b + b2b), score2 fused ----
  mm2r<KP1, true, true, true, true>(sY, sAg, &sW[B2A_OFF], &sW[W2B_OFF], sH,
                                    &sW[B2B_OFF], &sW[PW2_OFF], &sW[NRM2_OFF],
                                    sScore, tid);
  __syncthreads();

  // ---- N: rank2 + attn2 + hp2 ----
  if (tid < KP1 * 4) {
    const int n = tid >> 2, q = tid & 3;
    const float s = sScore[n];
    int r = 0;
    for (int m = q * 25; m < q * 25 + 25; ++m) {
      const float sm = sScore[m];
      r += (sm > s) || (sm == s && m < n);
    }
    r += __shfl_xor(r, 1);
    r += __shfl_xor(r, 2);
    if (q == 0) {
      sNewid[n] = (r < KP2) ? r : -1;
      if (r < KP2)
        out[2 * NGRAPH + NGRAPH * KP1 + g * KP2 + r] = 1.f / (1.f + expf(-s));
    }
    if (r < KP2) {
#pragma unroll
      for (int c = 0; c < 2; ++c) {
        const int ch = q * 2 + c;
        float4 v = *(const float4*)&sH[swz(n, ch)];
        v.x *= s; v.y *= s; v.z *= s; v.w *= s;
        *(float4*)&sHp[swz(r, ch)] = v;
      }
    }
  }
  __syncthreads();

  // ---- Q: x2 readout (64 thr), z = x1 + x2 ----
  if (tid < 64) {
    const int idx = tid & 31, seg = tid >> 5;
    const int ch = idx >> 2, w = idx & 3;
    float m = -INFINITY, s = 0.f;
    for (int r = seg * 25; r < seg * 25 + 25; ++r) {
      const float v = sHp[swz(r, ch) + w];
      m = fmaxf(m, v); s += v;
    }
    m = fmaxf(m, __shfl_xor(m, 32));
    s += __shfl_xor(s, 32);
    if (seg == 0) {
      sZ[idx] += m;
      sZ[32 + idx] += s / (float)KP2;
    }
  }
  __syncthreads();

  // ---- R: fc1 + bn1 (512 thr, split-K 4-way) ----
  if (tid < 512) {
    const int o = tid >> 2, q = tid & 3;
    float a = 0.f;
    for (int k = q * 16; k < q * 16 + 16; ++k) a += sZ[k] * fc1w[k * 128 + o];
    a += __shfl_xor(a, 1);
    a += __shfl_xor(a, 2);
    if (q == 0) {
      a += fc1b[o];
      a = fmaxf(a, 0.f);
      a = (a - bn1m[o]) * rsqrtf(bn1v[o] + 1e-5f) * bn1g[o] + bn1b[o];
      sZ1[o] = a;
    }
  }
  __syncthreads();

  // ---- S: fc2 + bn2 (512 thr, split-K 2-way) ----
  if (tid < 512) {
    const int o = tid >> 1, h = tid & 1;
    float a = 0.f;
    for (int k = h * 64; k < h * 64 + 64; ++k) a += sZ1[k] * fc2w[k * 256 + o];
    a += __shfl_xor(a, 1);
    if (h == 0) {
      a += fc2b[o];
      a = fmaxf(a, 0.f);
      a = (a - bn2m[o]) * rsqrtf(bn2v[o] + 1e-5f) * bn2g[o] + bn2b[o];
      sZ2[o] = a;
    }
  }
  __syncthreads();

  // ---- T: fc3 + log-softmax (one wave) ----
  if (tid < 64) {
    const int k4 = tid * 4;
    float a0 = 0.f, a1 = 0.f;
#pragma unroll
    for (int k = 0; k < 4; ++k) {
      const float z = sZ2[k4 + k];
      a0 += z * fc3w[(k4 + k) * 2 + 0];
      a1 += z * fc3w[(k4 + k) * 2 + 1];
    }
#pragma unroll
    for (int off = 32; off; off >>= 1) {
      a0 += __shfl_xor(a0, off);
      a1 += __shfl_xor(a1, off);
    }
    if (tid == 0) {
      const float l0 = a0 + fc3b[0], l1 = a1 + fc3b[1];
      const float mx = fmaxf(l0, l1);
      const float lse = mx + logf(expf(l0 - mx) + expf(l1 - mx));
      out[g * 2 + 0] = l0 - lse;
      out[g * 2 + 1] = l1 - lse;
    }
  }
}

extern "C" void kernel_launch(void* const* d_in, const int* in_sizes, int n_in,
                              void* d_out, int out_size, void* d_ws,
                              size_t ws_size, hipStream_t stream) {
  (void)in_sizes; (void)n_in; (void)out_size; (void)d_ws; (void)ws_size;
  gin_fused<<<NGRAPH, 1024, 0, stream>>>(
      (const float*)d_in[0], (const int*)d_in[1],
      (const float*)d_in[3], (const float*)d_in[4],
      (const float*)d_in[5], (const float*)d_in[6],
      (const float*)d_in[7], (const float*)d_in[8],
      (const float*)d_in[9], (const float*)d_in[10],
      (const float*)d_in[11], (const float*)d_in[12],
      (const float*)d_in[13], (const float*)d_in[14],
      (const float*)d_in[15], (const float*)d_in[16],
      (const float*)d_in[17], (const float*)d_in[18],
      (const float*)d_in[19], (const float*)d_in[20],
      (const float*)d_in[21], (const float*)d_in[22],
      (const float*)d_in[23], (const float*)d_in[24],
      (const float*)d_in[25], (const float*)d_in[26],
      (float*)d_out);
}

// Round 9
// 47.406 us; speedup vs baseline: 1.0684x; 1.0684x over previous
//
#include <hip/hip_runtime.h>
#include <math.h>

#define NGRAPH 128
#define NNODE  200
#define FIN    200
#define DIM    32
#define EPER   6400
#define ETOT   819200
#define KP1    100
#define KP2    50

// sW layout offsets (floats)
#define W1B_OFF  0
#define W2A_OFF  1024
#define W2B_OFF  2048
#define B1A_OFF  3072
#define B1B_OFF  3104
#define B2A_OFF  3136
#define B2B_OFF  3168
#define PW1_OFF  3200
#define PW2_OFF  3232
#define NRM1_OFF 3264
#define NRM2_OFF 3265
#define SW_SIZE  3280

// XOR chunk swizzle for [row][32]-float LDS tiles.
__device__ __forceinline__ int swz(int row, int chunk) {
  return (row << 5) + (((chunk ^ ((row >> 2) & 7))) << 2);
}

__device__ __forceinline__ void spin_eq(const int* f, int target) {
  while (__hip_atomic_load(f, __ATOMIC_RELAXED,
                           __HIP_MEMORY_SCOPE_WORKGROUP) != target)
    __builtin_amdgcn_s_sleep(1);
}

// [ROWS]x32 @ 32x32, 2 rows/thread (tid < ROWS*2).
// FUSE: A-operand = relu(A[p] + A2[p] + fb[chunk]) on the fly (GIN add+relu).
// SCORE: also emit pool score tanh(dot(h_row, pw)/nrm) via 4-lane shfl reduce.
template <int ROWS, bool RELU, bool BIAS, bool FUSE, bool SCORE>
__device__ __forceinline__ void mm2r(const float* __restrict__ A,
                                     const float* __restrict__ A2,
                                     const float* __restrict__ fb,
                                     const float* __restrict__ W,
                                     float* __restrict__ O,
                                     const float* __restrict__ bias,
                                     const float* __restrict__ pw,
                                     const float* __restrict__ nrmp,
                                     float* __restrict__ scoreOut, int tid) {
  if (tid < ROWS * 2) {
    const int rg = tid >> 2, cg = tid & 3;
    const int r0 = rg * 2, d0 = cg * 8;
    float acc[2][8];
#pragma unroll
    for (int r = 0; r < 2; ++r)
#pragma unroll
      for (int c = 0; c < 8; ++c) acc[r][c] = 0.f;
#pragma unroll
    for (int kc = 0; kc < 8; ++kc) {
      float4 av[2];
#pragma unroll
      for (int r = 0; r < 2; ++r) {
        const int p = swz(r0 + r, kc);
        float4 v = *(const float4*)&A[p];
        if (FUSE) {
          const float4 u = *(const float4*)&A2[p];
          const float4 b = *(const float4*)&fb[kc * 4];
          v.x = fmaxf(v.x + u.x + b.x, 0.f);
          v.y = fmaxf(v.y + u.y + b.y, 0.f);
          v.z = fmaxf(v.z + u.z + b.z, 0.f);
          v.w = fmaxf(v.w + u.w + b.w, 0.f);
        }
        av[r] = v;
      }
#pragma unroll
      for (int j = 0; j < 4; ++j) {
        const int k = kc * 4 + j;
        const float4 wa = *(const float4*)&W[k * 32 + d0];
        const float4 wb = *(const float4*)&W[k * 32 + d0 + 4];
#pragma unroll
        for (int r = 0; r < 2; ++r) {
          const float xs = (j == 0) ? av[r].x : (j == 1) ? av[r].y
                                  : (j == 2) ? av[r].z : av[r].w;
          acc[r][0] += xs * wa.x; acc[r][1] += xs * wa.y;
          acc[r][2] += xs * wa.z; acc[r][3] += xs * wa.w;
          acc[r][4] += xs * wb.x; acc[r][5] += xs * wb.y;
          acc[r][6] += xs * wb.z; acc[r][7] += xs * wb.w;
        }
      }
    }
    float dot[2] = {0.f, 0.f};
#pragma unroll
    for (int r = 0; r < 2; ++r) {
      float v[8];
#pragma unroll
      for (int c = 0; c < 8; ++c) {
        float t = acc[r][c];
        if (BIAS) t += bias[d0 + c];
        if (RELU) t = fmaxf(t, 0.f);
        v[c] = t;
      }
      if (SCORE) {
        float d = 0.f;
#pragma unroll
        for (int c = 0; c < 8; ++c) d += v[c] * pw[d0 + c];
        dot[r] = d;
      }
      float4 o0, o1;
      o0.x = v[0]; o0.y = v[1]; o0.z = v[2]; o0.w = v[3];
      o1.x = v[4]; o1.y = v[5]; o1.z = v[6]; o1.w = v[7];
      *(float4*)&O[swz(r0 + r, cg * 2)] = o0;
      *(float4*)&O[swz(r0 + r, cg * 2 + 1)] = o1;
    }
    if (SCORE) {
      dot[0] += __shfl_xor(dot[0], 1); dot[0] += __shfl_xor(dot[0], 2);
      dot[1] += __shfl_xor(dot[1], 1); dot[1] += __shfl_xor(dot[1], 2);
      if ((tid & 3) == 0) {
        const float nrm = *nrmp;
        scoreOut[r0] = tanhf(dot[0] / nrm);
        scoreOut[r0 + 1] = tanhf(dot[1] / nrm);
      }
    }
  }
}

// exclusive prefix over 256 counters (4-padded) by one full wave; lane 0..63
__device__ __forceinline__ void scan_counts(const int* __restrict__ cnt,
                                            int* __restrict__ start, int lane) {
  const int b = lane * 4;
  const int c0 = (cnt[b + 0] + 3) & ~3;
  const int c1 = (cnt[b + 1] + 3) & ~3;
  const int c2 = (cnt[b + 2] + 3) & ~3;
  const int c3 = (cnt[b + 3] + 3) & ~3;
  const int t01 = c0 + c1;
  const int t012 = t01 + c2;
  const int tot = t012 + c3;
  int run = tot;
#pragma unroll
  for (int off = 1; off < 64; off <<= 1) {
    const int t = __shfl_up(run, off);
    if (lane >= off) run += t;
  }
  const int e = run - tot;
  start[b + 0] = e;
  start[b + 1] = e + c0;
  start[b + 2] = e + t01;
  start[b + 3] = e + t012;
}

// 128 node-slots x 8 float4-parts
template <int NN>
__device__ __forceinline__ void aggregate(const float* __restrict__ sYv,
                                          float* __restrict__ sAgv,
                                          const int* __restrict__ sSrcv,
                                          const int* __restrict__ sStartv,
                                          const int* __restrict__ sCntv, int tid) {
  const int slot = tid >> 3, part = tid & 7;
#pragma unroll
  for (int p = 0; p < (NN + 127) / 128; ++p) {
    const int n = p * 128 + slot;
    if (n < NN) {
      const int jb = sStartv[n];
      const int je = jb + sCntv[n];
      float4 a0 = {0, 0, 0, 0}, a1 = {0, 0, 0, 0}, a2 = {0, 0, 0, 0}, a3 = {0, 0, 0, 0};
      int j = jb;
      for (; j + 4 <= je; j += 4) {
        const int4 ss = *(const int4*)&sSrcv[j];
        const float4 v0 = *(const float4*)&sYv[swz(ss.x, part)];
        const float4 v1 = *(const float4*)&sYv[swz(ss.y, part)];
        const float4 v2 = *(const float4*)&sYv[swz(ss.z, part)];
        const float4 v3 = *(const float4*)&sYv[swz(ss.w, part)];
        a0.x += v0.x; a0.y += v0.y; a0.z += v0.z; a0.w += v0.w;
        a1.x += v1.x; a1.y += v1.y; a1.z += v1.z; a1.w += v1.w;
        a2.x += v2.x; a2.y += v2.y; a2.z += v2.z; a2.w += v2.w;
        a3.x += v3.x; a3.y += v3.y; a3.z += v3.z; a3.w += v3.w;
      }
      for (; j < je; ++j) {
        const float4 v = *(const float4*)&sYv[swz(sSrcv[j], part)];
        a0.x += v.x; a0.y += v.y; a0.z += v.z; a0.w += v.w;
      }
      float4 o;
      o.x = (a0.x + a1.x) + (a2.x + a3.x);
      o.y = (a0.y + a1.y) + (a2.y + a3.y);
      o.z = (a0.z + a1.z) + (a2.z + a3.z);
      o.w = (a0.w + a1.w) + (a2.w + a3.w);
      *(float4*)&sAgv[swz(n, part)] = o;
    }
  }
}

// ============ single fused kernel: one block per graph ======
__global__ __launch_bounds__(1024, 1) void gin_fused(
    const float* __restrict__ x, const int* __restrict__ ei,
    const float* __restrict__ w1a, const float* __restrict__ b1a,
    const float* __restrict__ w1b, const float* __restrict__ b1b,
    const float* __restrict__ w2a, const float* __restrict__ b2a,
    const float* __restrict__ w2b, const float* __restrict__ b2b,
    const float* __restrict__ pw1, const float* __restrict__ pw2,
    const float* __restrict__ fc1w, const float* __restrict__ fc1b,
    const float* __restrict__ fc2w, const float* __restrict__ fc2b,
    const float* __restrict__ fc3w, const float* __restrict__ fc3b,
    const float* __restrict__ bn1g, const float* __restrict__ bn1b,
    const float* __restrict__ bn1m, const float* __restrict__ bn1v,
    const float* __restrict__ bn2g, const float* __restrict__ bn2b,
    const float* __restrict__ bn2m, const float* __restrict__ bn2v,
    float* __restrict__ out) {
  __shared__ __align__(16) float sY[6400];    // y1 (swz), later y2
  __shared__ __align__(16) float sAg[6400];   // w1a during proj, then aggr
  __shared__ __align__(16) float sH[6400];    // conv outputs (swz)
  __shared__ __align__(16) float sHp[3200];   // pooled h (swz)
  __shared__ __align__(16) float sW[SW_SIZE];
  __shared__ __align__(16) int sSrc[7040];    // 4-aligned CSR src lists
  __shared__ unsigned short sEdge[6400];      // packed (src<<8)|dst
  __shared__ int sCnt[256], sStart[256], sOfs[256];
  __shared__ int sCnt2[256], sStart2[256], sOfs2[256];
  __shared__ int sFlag[8];
  __shared__ float sScore[256];
  __shared__ int sNewid[256];
  __shared__ float sZ[64];
  __shared__ float sZ1[128];
  __shared__ float sZ2[256];

  const int tid = threadIdx.x;
  const int lane = tid & 63;
  const int g = blockIdx.x;

  // ===== A: balanced staging phase (one barrier) =====
  if (tid < 256) {
    // counters + flags + small vectors
    sCnt[tid] = 0; sOfs[tid] = 0; sCnt2[tid] = 0; sOfs2[tid] = 0;
    if (tid < 8) sFlag[tid] = 0;
    if (tid < 32) {
      sW[B1A_OFF + tid] = b1a[tid];
      sW[B1B_OFF + tid] = b1b[tid];
      sW[B2A_OFF + tid] = b2a[tid];
      sW[B2B_OFF + tid] = b2b[tid];
      sW[PW1_OFF + tid] = pw1[tid];
      sW[PW2_OFF + tid] = pw2[tid];
    }
  } else if (tid < 512) {
    // stage w1a (linear) into sAg
    for (int i = tid - 256; i < 1600; i += 256)
      ((float4*)sAg)[i] = ((const float4*)w1a)[i];
  } else {
    // pack edges + stage mm weights
    const int t = tid - 512;  // 0..511
    const int eb = g * EPER, nb = g * NNODE;
    for (int i = t; i < EPER / 4; i += 512) {
      const int4 ss = *(const int4*)&ei[eb + i * 4];
      const int4 dd = *(const int4*)&ei[ETOT + eb + i * 4];
      sEdge[i * 4 + 0] = (unsigned short)(((ss.x - nb) << 8) | (dd.x - nb));
      sEdge[i * 4 + 1] = (unsigned short)(((ss.y - nb) << 8) | (dd.y - nb));
      sEdge[i * 4 + 2] = (unsigned short)(((ss.z - nb) << 8) | (dd.z - nb));
      sEdge[i * 4 + 3] = (unsigned short)(((ss.w - nb) << 8) | (dd.w - nb));
    }
    for (int i = t; i < 768; i += 512) {
      const float4 v = (i < 256) ? ((const float4*)w1b)[i]
                    : (i < 512) ? ((const float4*)w2a)[i - 256]
                                : ((const float4*)w2b)[i - 512];
      const int off = (i < 256) ? W1B_OFF + i * 4
                    : (i < 512) ? W2A_OFF + (i - 256) * 4
                                : W2B_OFF + (i - 512) * 4;
      *(float4*)&sW[off] = v;
    }
  }
  __syncthreads();

  // ===== B: proj on 800 threads || norms || CSR1 on waves 13-15 =====
  if (tid < 800) {
    // y1 = x_g @ w1a : 2 rows x 4 cols/thread, ascending k (numerics-validated
    // mapping). 13 waves issue x-loads -> TLP hides HBM.
    const int rg = tid >> 3, cg = tid & 7;
    const int n0 = rg * 2, d0 = cg * 4;
    float a0[4] = {0, 0, 0, 0}, a1[4] = {0, 0, 0, 0};
    const float* xg = x + ((size_t)g * NNODE + n0) * FIN;
    for (int k = 0; k < FIN; k += 8) {
      const float4 xa0 = *(const float4*)&xg[k];
      const float4 xa1 = *(const float4*)&xg[k + 4];
      const float4 xb0 = *(const float4*)&xg[FIN + k];
      const float4 xb1 = *(const float4*)&xg[FIN + k + 4];
#pragma unroll
      for (int h = 0; h < 2; ++h) {
#pragma unroll
        for (int j = 0; j < 4; ++j) {
          const int kk = k + h * 4 + j;
          const float4 w = *(const float4*)&sAg[kk * 32 + d0];
          const float s0 = (h == 0) ? ((j == 0) ? xa0.x : (j == 1) ? xa0.y
                                      : (j == 2) ? xa0.z : xa0.w)
                                    : ((j == 0) ? xa1.x : (j == 1) ? xa1.y
                                      : (j == 2) ? xa1.z : xa1.w);
          const float s1 = (h == 0) ? ((j == 0) ? xb0.x : (j == 1) ? xb0.y
                                      : (j == 2) ? xb0.z : xb0.w)
                                    : ((j == 0) ? xb1.x : (j == 1) ? xb1.y
                                      : (j == 2) ? xb1.z : xb1.w);
          a0[0] += s0 * w.x; a0[1] += s0 * w.y;
          a0[2] += s0 * w.z; a0[3] += s0 * w.w;
          a1[0] += s1 * w.x; a1[1] += s1 * w.y;
          a1[2] += s1 * w.z; a1[3] += s1 * w.w;
        }
      }
    }
    float4 o;
    o.x = a0[0]; o.y = a0[1]; o.z = a0[2]; o.w = a0[3];
    *(float4*)&sY[swz(n0, cg)] = o;
    o.x = a1[0]; o.y = a1[1]; o.z = a1[2]; o.w = a1[3];
    *(float4*)&sY[swz(n0 + 1, cg)] = o;
  } else if (tid == 800) {
    float s = 0.f;
    for (int k = 0; k < 32; ++k) s += sW[PW1_OFF + k] * sW[PW1_OFF + k];
    sW[NRM1_OFF] = sqrtf(s);
  } else if (tid == 801) {
    float s = 0.f;
    for (int k = 0; k < 32; ++k) s += sW[PW2_OFF + k] * sW[PW2_OFF + k];
    sW[NRM2_OFF] = sqrtf(s);
  } else if (tid >= 832) {
    // CSR1 build on waves 13-15 (192 threads): count -> scan -> scatter
    const int t = tid - 832;  // 0..191
    for (int i = t; i < 800; i += 192) {  // 8 edges per uint4
      const uint4 u = *(const uint4*)&sEdge[i * 8];
      atomicAdd(&sCnt[u.x & 255], 1);
      atomicAdd(&sCnt[(u.x >> 16) & 255], 1);
      atomicAdd(&sCnt[u.y & 255], 1);
      atomicAdd(&sCnt[(u.y >> 16) & 255], 1);
      atomicAdd(&sCnt[u.z & 255], 1);
      atomicAdd(&sCnt[(u.z >> 16) & 255], 1);
      atomicAdd(&sCnt[u.w & 255], 1);
      atomicAdd(&sCnt[(u.w >> 16) & 255], 1);
    }
    __threadfence_block();
    if (lane == 0) atomicAdd(&sFlag[1], 1);
    if (tid >= 960) {  // wave 15 scans
      spin_eq(&sFlag[1], 3);
      scan_counts(sCnt, sStart, tid - 960);
      __threadfence_block();
      if (tid == 960) atomicExch(&sFlag[2], 1);
    }
    spin_eq(&sFlag[2], 1);
    for (int e = t; e < EPER; e += 192) {
      const unsigned short p = sEdge[e];
      sSrc[sStart[p & 255] + atomicAdd(&sOfs[p & 255], 1)] = p >> 8;
    }
  }
  __syncthreads();

  // ---- E: aggr1 ----
  aggregate<NNODE>(sY, sAg, sSrc, sStart, sCnt, tid);
  __syncthreads();

  // ---- F: h = relu(relu(y1+aggr1+b1a) @ w1b + b1b), score1 fused ----
  mm2r<200, true, true, true, true>(sY, sAg, &sW[B1A_OFF], &sW[W1B_OFF], sH,
                                    &sW[B1B_OFF], &sW[PW1_OFF], &sW[NRM1_OFF],
                                    sScore, tid);
  __syncthreads();

  // ---- H: rank1 (stable descending == lax.top_k) + attn1 + hp1 ----
  if (tid < NNODE * 4) {
    const int n = tid >> 2, q = tid & 3;
    const float s = sScore[n];
    int r = 0;
    for (int m = q * 50; m < q * 50 + 50; ++m) {
      const float sm = sScore[m];
      r += (sm > s) || (sm == s && m < n);
    }
    r += __shfl_xor(r, 1);
    r += __shfl_xor(r, 2);
    if (q == 0) {
      sNewid[n] = (r < KP1) ? r : -1;
      if (r < KP1) out[2 * NGRAPH + g * KP1 + r] = 1.f / (1.f + expf(-s));
    }
    if (r < KP1) {
#pragma unroll
      for (int c = 0; c < 2; ++c) {
        const int ch = q * 2 + c;
        float4 v = *(const float4*)&sH[swz(n, ch)];
        v.x *= s; v.y *= s; v.z *= s; v.w *= s;
        *(float4*)&sHp[swz(r, ch)] = v;
      }
    }
  }
  __syncthreads();

  // ---- I: y2 = hp1 @ w2a (t<200) || x1 readout (wave 4) || CSR2 (512+) ----
  mm2r<KP1, false, false, false, false>(sHp, nullptr, nullptr, &sW[W2A_OFF],
                                        sY, nullptr, nullptr, nullptr, nullptr,
                                        tid);
  if (tid >= 256 && tid < 320) {
    const int l = tid - 256;
    const int idx = l & 31, seg = l >> 5;
    const int ch = idx >> 2, w = idx & 3;
    float m = -INFINITY, s = 0.f;
    for (int r = seg * 50; r < seg * 50 + 50; ++r) {
      const float v = sHp[swz(r, ch) + w];
      m = fmaxf(m, v); s += v;
    }
    m = fmaxf(m, __shfl_xor(m, 32));
    s += __shfl_xor(s, 32);
    if (seg == 0) {
      sZ[idx] = m;
      sZ[32 + idx] = s / (float)KP1;
    }
  } else if (tid >= 512) {
    for (int e = tid - 512; e < EPER; e += 512) {
      const unsigned short p = sEdge[e];
      const int s1 = sNewid[p >> 8], d1 = sNewid[p & 255];
      if (s1 >= 0 && d1 >= 0) atomicAdd(&sCnt2[d1], 1);
    }
    __threadfence_block();
    if (lane == 0) atomicAdd(&sFlag[4], 1);
    if (tid >= 960) {  // wave 15 scans
      spin_eq(&sFlag[4], 8);
      scan_counts(sCnt2, sStart2, tid - 960);
      __threadfence_block();
      if (tid == 960) atomicExch(&sFlag[5], 1);
    }
    spin_eq(&sFlag[5], 1);
    for (int e = tid - 512; e < EPER; e += 512) {
      const unsigned short p = sEdge[e];
      const int s1 = sNewid[p >> 8], d1 = sNewid[p & 255];
      if (s1 >= 0 && d1 >= 0)
        sSrc[sStart2[d1] + atomicAdd(&sOfs2[d1], 1)] = s1;
    }
  }
  __syncthreads();

  // ---- L: aggr2 ----
  aggregate<KP1>(sY, sAg, sSrc, sStart2, sCnt2, tid);
  __syncthreads();

  // ---- M: hc2 = relu(relu(y2+aggr2+b2a) @ w2b + b2b), score2 fused ----
  mm2r<KP1, true, true, true, true>(sY, sAg, &sW[B2A_OFF], &sW[W2B_OFF], sH,
                                    &sW[B2B_OFF], &sW[PW2_OFF], &sW[NRM2_OFF],
                                    sScore, tid);
  __syncthreads();

  // ---- N: rank2 + attn2 + hp2 ----
  if (tid < KP1 * 4) {
    const int n = tid >> 2, q = tid & 3;
    const float s = sScore[n];
    int r = 0;
    for (int m = q * 25; m < q * 25 + 25; ++m) {
      const float sm = sScore[m];
      r += (sm > s) || (sm == s && m < n);
    }
    r += __shfl_xor(r, 1);
    r += __shfl_xor(r, 2);
    if (q == 0) {
      sNewid[n] = (r < KP2) ? r : -1;
      if (r < KP2)
        out[2 * NGRAPH + NGRAPH * KP1 + g * KP2 + r] = 1.f / (1.f + expf(-s));
    }
    if (r < KP2) {
#pragma unroll
      for (int c = 0; c < 2; ++c) {
        const int ch = q * 2 + c;
        float4 v = *(const float4*)&sH[swz(n, ch)];
        v.x *= s; v.y *= s; v.z *= s; v.w *= s;
        *(float4*)&sHp[swz(r, ch)] = v;
      }
    }
  }
  __syncthreads();

  // ---- Q: x2 readout (64 thr), z = x1 + x2 ----
  if (tid < 64) {
    const int idx = tid & 31, seg = tid >> 5;
    const int ch = idx >> 2, w = idx & 3;
    float m = -INFINITY, s = 0.f;
    for (int r = seg * 25; r < seg * 25 + 25; ++r) {
      const float v = sHp[swz(r, ch) + w];
      m = fmaxf(m, v); s += v;
    }
    m = fmaxf(m, __shfl_xor(m, 32));
    s += __shfl_xor(s, 32);
    if (seg == 0) {
      sZ[idx] += m;
      sZ[32 + idx] += s / (float)KP2;
    }
  }
  __syncthreads();

  // ---- R: fc1 + bn1 (512 thr, split-K 4-way) ----
  if (tid < 512) {
    const int o = tid >> 2, q = tid & 3;
    float a = 0.f;
    for (int k = q * 16; k < q * 16 + 16; ++k) a += sZ[k] * fc1w[k * 128 + o];
    a += __shfl_xor(a, 1);
    a += __shfl_xor(a, 2);
    if (q == 0) {
      a += fc1b[o];
      a = fmaxf(a, 0.f);
      a = (a - bn1m[o]) * rsqrtf(bn1v[o] + 1e-5f) * bn1g[o] + bn1b[o];
      sZ1[o] = a;
    }
  }
  __syncthreads();

  // ---- S: fc2 + bn2 (512 thr, split-K 2-way) ----
  if (tid < 512) {
    const int o = tid >> 1, h = tid & 1;
    float a = 0.f;
    for (int k = h * 64; k < h * 64 + 64; ++k) a += sZ1[k] * fc2w[k * 256 + o];
    a += __shfl_xor(a, 1);
    if (h == 0) {
      a += fc2b[o];
      a = fmaxf(a, 0.f);
      a = (a - bn2m[o]) * rsqrtf(bn2v[o] + 1e-5f) * bn2g[o] + bn2b[o];
      sZ2[o] = a;
    }
  }
  __syncthreads();

  // ---- T: fc3 + log-softmax (one wave) ----
  if (tid < 64) {
    const int k4 = tid * 4;
    float a0 = 0.f, a1 = 0.f;
#pragma unroll
    for (int k = 0; k < 4; ++k) {
      const float z = sZ2[k4 + k];
      a0 += z * fc3w[(k4 + k) * 2 + 0];
      a1 += z * fc3w[(k4 + k) * 2 + 1];
    }
#pragma unroll
    for (int off = 32; off; off >>= 1) {
      a0 += __shfl_xor(a0, off);
      a1 += __shfl_xor(a1, off);
    }
    if (tid == 0) {
      const float l0 = a0 + fc3b[0], l1 = a1 + fc3b[1];
      const float mx = fmaxf(l0, l1);
      const float lse = mx + logf(expf(l0 - mx) + expf(l1 - mx));
      out[g * 2 + 0] = l0 - lse;
      out[g * 2 + 1] = l1 - lse;
    }
  }
}

extern "C" void kernel_launch(void* const* d_in, const int* in_sizes, int n_in,
                              void* d_out, int out_size, void* d_ws,
                              size_t ws_size, hipStream_t stream) {
  (void)in_sizes; (void)n_in; (void)out_size; (void)d_ws; (void)ws_size;
  gin_fused<<<NGRAPH, 1024, 0, stream>>>(
      (const float*)d_in[0], (const int*)d_in[1],
      (const float*)d_in[3], (const float*)d_in[4],
      (const float*)d_in[5], (const float*)d_in[6],
      (const float*)d_in[7], (const float*)d_in[8],
      (const float*)d_in[9], (const float*)d_in[10],
      (const float*)d_in[11], (const float*)d_in[12],
      (const float*)d_in[13], (const float*)d_in[14],
      (const float*)d_in[15], (const float*)d_in[16],
      (const float*)d_in[17], (const float*)d_in[18],
      (const float*)d_in[19], (const float*)d_in[20],
      (const float*)d_in[21], (const float*)d_in[22],
      (const float*)d_in[23], (const float*)d_in[24],
      (const float*)d_in[25], (const float*)d_in[26],
      (float*)d_out);
}

// Round 10
// 46.079 us; speedup vs baseline: 1.0992x; 1.0288x over previous
//
#include <hip/hip_runtime.h>
#include <math.h>

#define NGRAPH 128
#define NNODE  200
#define FIN    200
#define DIM    32
#define EPER   6400
#define ETOT   819200
#define KP1    100
#define KP2    50

// sW layout offsets (floats)
#define W1B_OFF  0
#define W2A_OFF  1024
#define W2B_OFF  2048
#define B1A_OFF  3072
#define B1B_OFF  3104
#define B2A_OFF  3136
#define B2B_OFF  3168
#define PW1_OFF  3200
#define PW2_OFF  3232
#define NRM1_OFF 3264
#define NRM2_OFF 3265
#define SW_SIZE  3280

// XOR chunk swizzle for [row][32]-float LDS tiles.
__device__ __forceinline__ int swz(int row, int chunk) {
  return (row << 5) + (((chunk ^ ((row >> 2) & 7))) << 2);
}

__device__ __forceinline__ void spin_eq(const int* f, int target) {
  while (__hip_atomic_load(f, __ATOMIC_RELAXED,
                           __HIP_MEMORY_SCOPE_WORKGROUP) != target)
    __builtin_amdgcn_s_sleep(1);
}

// [ROWS]x32 @ 32x32, 2 rows/thread (tid < ROWS*2).
// FUSE: A-operand = relu(A[p] + A2[p] + fb[chunk]) on the fly (GIN add+relu).
// SCORE: also emit pool score tanh(dot(h_row, pw)/nrm) via 4-lane shfl reduce.
template <int ROWS, bool RELU, bool BIAS, bool FUSE, bool SCORE>
__device__ __forceinline__ void mm2r(const float* __restrict__ A,
                                     const float* __restrict__ A2,
                                     const float* __restrict__ fb,
                                     const float* __restrict__ W,
                                     float* __restrict__ O,
                                     const float* __restrict__ bias,
                                     const float* __restrict__ pw,
                                     const float* __restrict__ nrmp,
                                     float* __restrict__ scoreOut, int tid) {
  if (tid < ROWS * 2) {
    const int rg = tid >> 2, cg = tid & 3;
    const int r0 = rg * 2, d0 = cg * 8;
    float acc[2][8];
#pragma unroll
    for (int r = 0; r < 2; ++r)
#pragma unroll
      for (int c = 0; c < 8; ++c) acc[r][c] = 0.f;
#pragma unroll
    for (int kc = 0; kc < 8; ++kc) {
      float4 av[2];
#pragma unroll
      for (int r = 0; r < 2; ++r) {
        const int p = swz(r0 + r, kc);
        float4 v = *(const float4*)&A[p];
        if (FUSE) {
          const float4 u = *(const float4*)&A2[p];
          const float4 b = *(const float4*)&fb[kc * 4];
          v.x = fmaxf(v.x + u.x + b.x, 0.f);
          v.y = fmaxf(v.y + u.y + b.y, 0.f);
          v.z = fmaxf(v.z + u.z + b.z, 0.f);
          v.w = fmaxf(v.w + u.w + b.w, 0.f);
        }
        av[r] = v;
      }
#pragma unroll
      for (int j = 0; j < 4; ++j) {
        const int k = kc * 4 + j;
        const float4 wa = *(const float4*)&W[k * 32 + d0];
        const float4 wb = *(const float4*)&W[k * 32 + d0 + 4];
#pragma unroll
        for (int r = 0; r < 2; ++r) {
          const float xs = (j == 0) ? av[r].x : (j == 1) ? av[r].y
                                  : (j == 2) ? av[r].z : av[r].w;
          acc[r][0] += xs * wa.x; acc[r][1] += xs * wa.y;
          acc[r][2] += xs * wa.z; acc[r][3] += xs * wa.w;
          acc[r][4] += xs * wb.x; acc[r][5] += xs * wb.y;
          acc[r][6] += xs * wb.z; acc[r][7] += xs * wb.w;
        }
      }
    }
    float dot[2] = {0.f, 0.f};
#pragma unroll
    for (int r = 0; r < 2; ++r) {
      float v[8];
#pragma unroll
      for (int c = 0; c < 8; ++c) {
        float t = acc[r][c];
        if (BIAS) t += bias[d0 + c];
        if (RELU) t = fmaxf(t, 0.f);
        v[c] = t;
      }
      if (SCORE) {
        float d = 0.f;
#pragma unroll
        for (int c = 0; c < 8; ++c) d += v[c] * pw[d0 + c];
        dot[r] = d;
      }
      float4 o0, o1;
      o0.x = v[0]; o0.y = v[1]; o0.z = v[2]; o0.w = v[3];
      o1.x = v[4]; o1.y = v[5]; o1.z = v[6]; o1.w = v[7];
      *(float4*)&O[swz(r0 + r, cg * 2)] = o0;
      *(float4*)&O[swz(r0 + r, cg * 2 + 1)] = o1;
    }
    if (SCORE) {
      dot[0] += __shfl_xor(dot[0], 1); dot[0] += __shfl_xor(dot[0], 2);
      dot[1] += __shfl_xor(dot[1], 1); dot[1] += __shfl_xor(dot[1], 2);
      if ((tid & 3) == 0) {
        const float nrm = *nrmp;
        scoreOut[r0] = tanhf(dot[0] / nrm);
        scoreOut[r0 + 1] = tanhf(dot[1] / nrm);
      }
    }
  }
}

// exclusive prefix over 256 counters (4-padded) by one full wave; lane 0..63
__device__ __forceinline__ void scan_counts(const int* __restrict__ cnt,
                                            int* __restrict__ start, int lane) {
  const int b = lane * 4;
  const int c0 = (cnt[b + 0] + 3) & ~3;
  const int c1 = (cnt[b + 1] + 3) & ~3;
  const int c2 = (cnt[b + 2] + 3) & ~3;
  const int c3 = (cnt[b + 3] + 3) & ~3;
  const int t01 = c0 + c1;
  const int t012 = t01 + c2;
  const int tot = t012 + c3;
  int run = tot;
#pragma unroll
  for (int off = 1; off < 64; off <<= 1) {
    const int t = __shfl_up(run, off);
    if (lane >= off) run += t;
  }
  const int e = run - tot;
  start[b + 0] = e;
  start[b + 1] = e + c0;
  start[b + 2] = e + t01;
  start[b + 3] = e + t012;
}

// 128 node-slots x 8 float4-parts
template <int NN>
__device__ __forceinline__ void aggregate(const float* __restrict__ sYv,
                                          float* __restrict__ sAgv,
                                          const int* __restrict__ sSrcv,
                                          const int* __restrict__ sStartv,
                                          const int* __restrict__ sCntv, int tid) {
  const int slot = tid >> 3, part = tid & 7;
#pragma unroll
  for (int p = 0; p < (NN + 127) / 128; ++p) {
    const int n = p * 128 + slot;
    if (n < NN) {
      const int jb = sStartv[n];
      const int je = jb + sCntv[n];
      float4 a0 = {0, 0, 0, 0}, a1 = {0, 0, 0, 0}, a2 = {0, 0, 0, 0}, a3 = {0, 0, 0, 0};
      int j = jb;
      for (; j + 4 <= je; j += 4) {
        const int4 ss = *(const int4*)&sSrcv[j];
        const float4 v0 = *(const float4*)&sYv[swz(ss.x, part)];
        const float4 v1 = *(const float4*)&sYv[swz(ss.y, part)];
        const float4 v2 = *(const float4*)&sYv[swz(ss.z, part)];
        const float4 v3 = *(const float4*)&sYv[swz(ss.w, part)];
        a0.x += v0.x; a0.y += v0.y; a0.z += v0.z; a0.w += v0.w;
        a1.x += v1.x; a1.y += v1.y; a1.z += v1.z; a1.w += v1.w;
        a2.x += v2.x; a2.y += v2.y; a2.z += v2.z; a2.w += v2.w;
        a3.x += v3.x; a3.y += v3.y; a3.z += v3.z; a3.w += v3.w;
      }
      for (; j < je; ++j) {
        const float4 v = *(const float4*)&sYv[swz(sSrcv[j], part)];
        a0.x += v.x; a0.y += v.y; a0.z += v.z; a0.w += v.w;
      }
      float4 o;
      o.x = (a0.x + a1.x) + (a2.x + a3.x);
      o.y = (a0.y + a1.y) + (a2.y + a3.y);
      o.z = (a0.z + a1.z) + (a2.z + a3.z);
      o.w = (a0.w + a1.w) + (a2.w + a3.w);
      *(float4*)&sAgv[swz(n, part)] = o;
    }
  }
}

// ============ single fused kernel: one block per graph ======
__global__ __launch_bounds__(1024, 1) void gin_fused(
    const float* __restrict__ x, const int* __restrict__ ei,
    const float* __restrict__ w1a, const float* __restrict__ b1a,
    const float* __restrict__ w1b, const float* __restrict__ b1b,
    const float* __restrict__ w2a, const float* __restrict__ b2a,
    const float* __restrict__ w2b, const float* __restrict__ b2b,
    const float* __restrict__ pw1, const float* __restrict__ pw2,
    const float* __restrict__ fc1w, const float* __restrict__ fc1b,
    const float* __restrict__ fc2w, const float* __restrict__ fc2b,
    const float* __restrict__ fc3w, const float* __restrict__ fc3b,
    const float* __restrict__ bn1g, const float* __restrict__ bn1b,
    const float* __restrict__ bn1m, const float* __restrict__ bn1v,
    const float* __restrict__ bn2g, const float* __restrict__ bn2b,
    const float* __restrict__ bn2m, const float* __restrict__ bn2v,
    float* __restrict__ out) {
  __shared__ __align__(16) float sY[6400];    // y1 (swz), later y2
  __shared__ __align__(16) float sAg[6400];   // w1a during proj, then aggr
  __shared__ __align__(16) float sH[6400];    // conv outputs (swz)
  __shared__ __align__(16) float sHp[3200];   // pooled h (swz)
  __shared__ __align__(16) float sW[SW_SIZE];
  __shared__ __align__(16) int sSrc[7040];    // 4-aligned CSR src lists
  __shared__ unsigned short sEdge[6400];      // packed (src<<8)|dst
  __shared__ int sCnt[256], sStart[256], sOfs[256];
  __shared__ int sCnt2[256], sStart2[256], sOfs2[256];
  __shared__ int sFlag[8];
  __shared__ float sScore[256];
  __shared__ int sNewid[256];
  __shared__ float sZ[64];
  __shared__ float sZ1[128];

  const int tid = threadIdx.x;
  const int lane = tid & 63;
  const int g = blockIdx.x;

  // ===== A: balanced staging phase (one barrier) =====
  if (tid < 256) {
    // counters + flags + small vectors
    sCnt[tid] = 0; sOfs[tid] = 0; sCnt2[tid] = 0; sOfs2[tid] = 0;
    if (tid < 8) sFlag[tid] = 0;
    if (tid < 32) {
      sW[B1A_OFF + tid] = b1a[tid];
      sW[B1B_OFF + tid] = b1b[tid];
      sW[B2A_OFF + tid] = b2a[tid];
      sW[B2B_OFF + tid] = b2b[tid];
      sW[PW1_OFF + tid] = pw1[tid];
      sW[PW2_OFF + tid] = pw2[tid];
    }
  } else if (tid < 512) {
    // stage w1a (linear) into sAg
    for (int i = tid - 256; i < 1600; i += 256)
      ((float4*)sAg)[i] = ((const float4*)w1a)[i];
  } else {
    // pack edges + stage mm weights
    const int t = tid - 512;  // 0..511
    const int eb = g * EPER, nb = g * NNODE;
    for (int i = t; i < EPER / 4; i += 512) {
      const int4 ss = *(const int4*)&ei[eb + i * 4];
      const int4 dd = *(const int4*)&ei[ETOT + eb + i * 4];
      sEdge[i * 4 + 0] = (unsigned short)(((ss.x - nb) << 8) | (dd.x - nb));
      sEdge[i * 4 + 1] = (unsigned short)(((ss.y - nb) << 8) | (dd.y - nb));
      sEdge[i * 4 + 2] = (unsigned short)(((ss.z - nb) << 8) | (dd.z - nb));
      sEdge[i * 4 + 3] = (unsigned short)(((ss.w - nb) << 8) | (dd.w - nb));
    }
    for (int i = t; i < 768; i += 512) {
      const float4 v = (i < 256) ? ((const float4*)w1b)[i]
                    : (i < 512) ? ((const float4*)w2a)[i - 256]
                                : ((const float4*)w2b)[i - 512];
      const int off = (i < 256) ? W1B_OFF + i * 4
                    : (i < 512) ? W2A_OFF + (i - 256) * 4
                                : W2B_OFF + (i - 512) * 4;
      *(float4*)&sW[off] = v;
    }
  }
  __syncthreads();

  // ===== B: proj on 800 threads || norms || CSR1 on waves 13-15 =====
  if (tid < 800) {
    // y1 = x_g @ w1a : 2 rows x 4 cols/thread, ascending k (numerics-validated
    // mapping). 13 waves issue x-loads -> TLP hides HBM.
    const int rg = tid >> 3, cg = tid & 7;
    const int n0 = rg * 2, d0 = cg * 4;
    float a0[4] = {0, 0, 0, 0}, a1[4] = {0, 0, 0, 0};
    const float* xg = x + ((size_t)g * NNODE + n0) * FIN;
    for (int k = 0; k < FIN; k += 8) {
      const float4 xa0 = *(const float4*)&xg[k];
      const float4 xa1 = *(const float4*)&xg[k + 4];
      const float4 xb0 = *(const float4*)&xg[FIN + k];
      const float4 xb1 = *(const float4*)&xg[FIN + k + 4];
#pragma unroll
      for (int h = 0; h < 2; ++h) {
#pragma unroll
        for (int j = 0; j < 4; ++j) {
          const int kk = k + h * 4 + j;
          const float4 w = *(const float4*)&sAg[kk * 32 + d0];
          const float s0 = (h == 0) ? ((j == 0) ? xa0.x : (j == 1) ? xa0.y
                                      : (j == 2) ? xa0.z : xa0.w)
                                    : ((j == 0) ? xa1.x : (j == 1) ? xa1.y
                                      : (j == 2) ? xa1.z : xa1.w);
          const float s1 = (h == 0) ? ((j == 0) ? xb0.x : (j == 1) ? xb0.y
                                      : (j == 2) ? xb0.z : xb0.w)
                                    : ((j == 0) ? xb1.x : (j == 1) ? xb1.y
                                      : (j == 2) ? xb1.z : xb1.w);
          a0[0] += s0 * w.x; a0[1] += s0 * w.y;
          a0[2] += s0 * w.z; a0[3] += s0 * w.w;
          a1[0] += s1 * w.x; a1[1] += s1 * w.y;
          a1[2] += s1 * w.z; a1[3] += s1 * w.w;
        }
      }
    }
    float4 o;
    o.x = a0[0]; o.y = a0[1]; o.z = a0[2]; o.w = a0[3];
    *(float4*)&sY[swz(n0, cg)] = o;
    o.x = a1[0]; o.y = a1[1]; o.z = a1[2]; o.w = a1[3];
    *(float4*)&sY[swz(n0 + 1, cg)] = o;
  } else if (tid == 800) {
    float s = 0.f;
    for (int k = 0; k < 32; ++k) s += sW[PW1_OFF + k] * sW[PW1_OFF + k];
    sW[NRM1_OFF] = sqrtf(s);
  } else if (tid == 801) {
    float s = 0.f;
    for (int k = 0; k < 32; ++k) s += sW[PW2_OFF + k] * sW[PW2_OFF + k];
    sW[NRM2_OFF] = sqrtf(s);
  } else if (tid >= 832) {
    // CSR1 build on waves 13-15 (192 threads): count -> scan -> scatter
    const int t = tid - 832;  // 0..191
    for (int i = t; i < 800; i += 192) {  // 8 edges per uint4
      const uint4 u = *(const uint4*)&sEdge[i * 8];
      atomicAdd(&sCnt[u.x & 255], 1);
      atomicAdd(&sCnt[(u.x >> 16) & 255], 1);
      atomicAdd(&sCnt[u.y & 255], 1);
      atomicAdd(&sCnt[(u.y >> 16) & 255], 1);
      atomicAdd(&sCnt[u.z & 255], 1);
      atomicAdd(&sCnt[(u.z >> 16) & 255], 1);
      atomicAdd(&sCnt[u.w & 255], 1);
      atomicAdd(&sCnt[(u.w >> 16) & 255], 1);
    }
    __threadfence_block();
    if (lane == 0) atomicAdd(&sFlag[1], 1);
    if (tid >= 960) {  // wave 15 scans
      spin_eq(&sFlag[1], 3);
      scan_counts(sCnt, sStart, tid - 960);
      __threadfence_block();
      if (tid == 960) atomicExch(&sFlag[2], 1);
    }
    spin_eq(&sFlag[2], 1);
    for (int e = t; e < EPER; e += 192) {
      const unsigned short p = sEdge[e];
      sSrc[sStart[p & 255] + atomicAdd(&sOfs[p & 255], 1)] = p >> 8;
    }
  }
  __syncthreads();

  // ---- E: aggr1 ----
  aggregate<NNODE>(sY, sAg, sSrc, sStart, sCnt, tid);
  __syncthreads();

  // ---- F: h = relu(relu(y1+aggr1+b1a) @ w1b + b1b), score1 fused ----
  mm2r<200, true, true, true, true>(sY, sAg, &sW[B1A_OFF], &sW[W1B_OFF], sH,
                                    &sW[B1B_OFF], &sW[PW1_OFF], &sW[NRM1_OFF],
                                    sScore, tid);
  __syncthreads();

  // ---- H: rank1 (stable descending == lax.top_k) + attn1 + hp1 ----
  if (tid < NNODE * 4) {
    const int n = tid >> 2, q = tid & 3;
    const float s = sScore[n];
    int r = 0;
    for (int m = q * 50; m < q * 50 + 50; ++m) {
      const float sm = sScore[m];
      r += (sm > s) || (sm == s && m < n);
    }
    r += __shfl_xor(r, 1);
    r += __shfl_xor(r, 2);
    if (q == 0) {
      sNewid[n] = (r < KP1) ? r : -1;
      if (r < KP1) out[2 * NGRAPH + g * KP1 + r] = 1.f / (1.f + expf(-s));
    }
    if (r < KP1) {
#pragma unroll
      for (int c = 0; c < 2; ++c) {
        const int ch = q * 2 + c;
        float4 v = *(const float4*)&sH[swz(n, ch)];
        v.x *= s; v.y *= s; v.z *= s; v.w *= s;
        *(float4*)&sHp[swz(r, ch)] = v;
      }
    }
  }
  __syncthreads();

  // ---- I: y2 = hp1 @ w2a (t<200) || x1 readout (wave 4) || CSR2 (512+) ----
  mm2r<KP1, false, false, false, false>(sHp, nullptr, nullptr, &sW[W2A_OFF],
                                        sY, nullptr, nullptr, nullptr, nullptr,
                                        tid);
  if (tid >= 256 && tid < 320) {
    const int l = tid - 256;
    const int idx = l & 31, seg = l >> 5;
    const int ch = idx >> 2, w = idx & 3;
    float m = -INFINITY, s = 0.f;
    for (int r = seg * 50; r < seg * 50 + 50; ++r) {
      const float v = sHp[swz(r, ch) + w];
      m = fmaxf(m, v); s += v;
    }
    m = fmaxf(m, __shfl_xor(m, 32));
    s += __shfl_xor(s, 32);
    if (seg == 0) {
      sZ[idx] = m;
      sZ[32 + idx] = s / (float)KP1;
    }
  } else if (tid >= 512) {
    for (int e = tid - 512; e < EPER; e += 512) {
      const unsigned short p = sEdge[e];
      const int s1 = sNewid[p >> 8], d1 = sNewid[p & 255];
      if (s1 >= 0 && d1 >= 0) atomicAdd(&sCnt2[d1], 1);
    }
    __threadfence_block();
    if (lane == 0) atomicAdd(&sFlag[4], 1);
    if (tid >= 960) {  // wave 15 scans
      spin_eq(&sFlag[4], 8);
      scan_counts(sCnt2, sStart2, tid - 960);
      __threadfence_block();
      if (tid == 960) atomicExch(&sFlag[5], 1);
    }
    spin_eq(&sFlag[5], 1);
    for (int e = tid - 512; e < EPER; e += 512) {
      const unsigned short p = sEdge[e];
      const int s1 = sNewid[p >> 8], d1 = sNewid[p & 255];
      if (s1 >= 0 && d1 >= 0)
        sSrc[sStart2[d1] + atomicAdd(&sOfs2[d1], 1)] = s1;
    }
  }
  __syncthreads();

  // ---- L: aggr2 ----
  aggregate<KP1>(sY, sAg, sSrc, sStart2, sCnt2, tid);
  __syncthreads();

  // ---- M: hc2 = relu(relu(y2+aggr2+b2a) @ w2b + b2b), score2 fused ----
  mm2r<KP1, true, true, true, true>(sY, sAg, &sW[B2A_OFF], &sW[W2B_OFF], sH,
                                    &sW[B2B_OFF], &sW[PW2_OFF], &sW[NRM2_OFF],
                                    sScore, tid);
  __syncthreads();

  // ---- N: rank2 + attn2 + hp2 ----
  if (tid < KP1 * 4) {
    const int n = tid >> 2, q = tid & 3;
    const float s = sScore[n];
    int r = 0;
    for (int m = q * 25; m < q * 25 + 25; ++m) {
      const float sm = sScore[m];
      r += (sm > s) || (sm == s && m < n);
    }
    r += __shfl_xor(r, 1);
    r += __shfl_xor(r, 2);
    if (q == 0) {
      sNewid[n] = (r < KP2) ? r : -1;
      if (r < KP2)
        out[2 * NGRAPH + NGRAPH * KP1 + g * KP2 + r] = 1.f / (1.f + expf(-s));
    }
    if (r < KP2) {
#pragma unroll
      for (int c = 0; c < 2; ++c) {
        const int ch = q * 2 + c;
        float4 v = *(const float4*)&sH[swz(n, ch)];
        v.x *= s; v.y *= s; v.z *= s; v.w *= s;
        *(float4*)&sHp[swz(r, ch)] = v;
      }
    }
  }
  __syncthreads();

  // ---- TAIL (single wave, wave-synchronous, no barriers):
  //      x2 readout -> z -> fc1+bn1 -> fc2+bn2 -> fc3 -> log-softmax ----
  if (tid < 64) {
    // x2 readout: col c, row-halves split across lane pairs (l, l+32)
    const int c = tid & 31, seg = tid >> 5;
    const int ch = c >> 2, w = c & 3;
    float m = -INFINITY, s = 0.f;
    for (int r = seg * 25; r < seg * 25 + 25; ++r) {
      const float v = sHp[swz(r, ch) + w];
      m = fmaxf(m, v); s += v;
    }
    m = fmaxf(m, __shfl_xor(m, 32));
    s += __shfl_xor(s, 32);
    if (seg == 0) {
      sZ[c] += m;
      sZ[32 + c] += s / (float)KP2;
    }
    __threadfence_block();  // sZ complete for this wave

    // fc1 + bn1: lane l -> outputs l and l+64
    const int l = tid;
    float a1 = fc1b[l], a2 = fc1b[l + 64];
    for (int k = 0; k < 64; ++k) {
      const float zk = sZ[k];
      a1 += zk * fc1w[k * 128 + l];
      a2 += zk * fc1w[k * 128 + l + 64];
    }
    a1 = fmaxf(a1, 0.f);
    a1 = (a1 - bn1m[l]) * rsqrtf(bn1v[l] + 1e-5f) * bn1g[l] + bn1b[l];
    a2 = fmaxf(a2, 0.f);
    a2 = (a2 - bn1m[l + 64]) * rsqrtf(bn1v[l + 64] + 1e-5f) * bn1g[l + 64] +
         bn1b[l + 64];
    sZ1[l] = a1;
    sZ1[l + 64] = a2;
    __threadfence_block();

    // fc2 + bn2: lane l -> outputs 4l..4l+3 (kept in registers)
    const int o4 = l * 4;
    float b0 = fc2b[o4], b1 = fc2b[o4 + 1], b2 = fc2b[o4 + 2], b3 = fc2b[o4 + 3];
    for (int k = 0; k < 128; ++k) {
      const float zk = sZ1[k];
      const float4 wv = *(const float4*)&fc2w[k * 256 + o4];
      b0 += zk * wv.x; b1 += zk * wv.y; b2 += zk * wv.z; b3 += zk * wv.w;
    }
    const float4 bm = *(const float4*)&bn2m[o4];
    const float4 bv = *(const float4*)&bn2v[o4];
    const float4 bg = *(const float4*)&bn2g[o4];
    const float4 bb = *(const float4*)&bn2b[o4];
    b0 = (fmaxf(b0, 0.f) - bm.x) * rsqrtf(bv.x + 1e-5f) * bg.x + bb.x;
    b1 = (fmaxf(b1, 0.f) - bm.y) * rsqrtf(bv.y + 1e-5f) * bg.y + bb.y;
    b2 = (fmaxf(b2, 0.f) - bm.z) * rsqrtf(bv.z + 1e-5f) * bg.z + bb.z;
    b3 = (fmaxf(b3, 0.f) - bm.w) * rsqrtf(bv.w + 1e-5f) * bg.w + bb.w;

    // fc3: lane partials over its 4 k-slots, butterfly reduce
    float a0s = b0 * fc3w[(o4 + 0) * 2 + 0] + b1 * fc3w[(o4 + 1) * 2 + 0] +
                b2 * fc3w[(o4 + 2) * 2 + 0] + b3 * fc3w[(o4 + 3) * 2 + 0];
    float a1s = b0 * fc3w[(o4 + 0) * 2 + 1] + b1 * fc3w[(o4 + 1) * 2 + 1] +
                b2 * fc3w[(o4 + 2) * 2 + 1] + b3 * fc3w[(o4 + 3) * 2 + 1];
#pragma unroll
    for (int off = 32; off; off >>= 1) {
      a0s += __shfl_xor(a0s, off);
      a1s += __shfl_xor(a1s, off);
    }
    if (tid == 0) {
      const float l0 = a0s + fc3b[0], l1 = a1s + fc3b[1];
      const float mx = fmaxf(l0, l1);
      const float lse = mx + logf(expf(l0 - mx) + expf(l1 - mx));
      out[g * 2 + 0] = l0 - lse;
      out[g * 2 + 1] = l1 - lse;
    }
  }
}

extern "C" void kernel_launch(void* const* d_in, const int* in_sizes, int n_in,
                              void* d_out, int out_size, void* d_ws,
                              size_t ws_size, hipStream_t stream) {
  (void)in_sizes; (void)n_in; (void)out_size; (void)d_ws; (void)ws_size;
  gin_fused<<<NGRAPH, 1024, 0, stream>>>(
      (const float*)d_in[0], (const int*)d_in[1],
      (const float*)d_in[3], (const float*)d_in[4],
      (const float*)d_in[5], (const float*)d_in[6],
      (const float*)d_in[7], (const float*)d_in[8],
      (const float*)d_in[9], (const float*)d_in[10],
      (const float*)d_in[11], (const float*)d_in[12],
      (const float*)d_in[13], (const float*)d_in[14],
      (const float*)d_in[15], (const float*)d_in[16],
      (const float*)d_in[17], (const float*)d_in[18],
      (const float*)d_in[19], (const float*)d_in[20],
      (const float*)d_in[21], (const float*)d_in[22],
      (const float*)d_in[23], (const float*)d_in[24],
      (const float*)d_in[25], (const float*)d_in[26],
      (float*)d_out);
}